// Round 3
// baseline (285.475 us; speedup 1.0000x reference)
//
#include <hip/hip_runtime.h>
#include <cstdint>
#include <cstddef>

typedef short bf16x8 __attribute__((ext_vector_type(8)));
typedef float f32x4 __attribute__((ext_vector_type(4)));
typedef unsigned short u16x4 __attribute__((ext_vector_type(4)));
typedef unsigned short u16x8 __attribute__((ext_vector_type(8)));

#define MFMA(a,b,c) __builtin_amdgcn_mfma_f32_16x16x32_bf16((a),(b),(c),0,0,0)

__device__ __forceinline__ unsigned short f2bf(float x){
  union { float f; unsigned u; } v; v.f = x;
  unsigned r = v.u + 0x7FFFu + ((v.u >> 16) & 1u);  // RNE
  return (unsigned short)(r >> 16);
}
__device__ __forceinline__ float bf2f(unsigned short b){
  union { unsigned u; float f; } v; v.u = ((unsigned)b) << 16;
  return v.f;
}
__device__ __forceinline__ bf16x8 cvtld8(const float* p){
  f32x4 a = *(const f32x4*)p;
  f32x4 b = *(const f32x4*)(p + 4);
  bf16x8 r;
  r[0]=(short)f2bf(a.x); r[1]=(short)f2bf(a.y);
  r[2]=(short)f2bf(a.z); r[3]=(short)f2bf(a.w);
  r[4]=(short)f2bf(b.x); r[5]=(short)f2bf(b.y);
  r[6]=(short)f2bf(b.z); r[7]=(short)f2bf(b.w);
  return r;
}

// ---------------- kernel 0: fp32 weights -> bf16 (wq,wk,wv,wg,wo) ----------
__global__ __launch_bounds__(256) void wcvt_kernel(
    const float* __restrict__ wq, const float* __restrict__ wk,
    const float* __restrict__ wv, const float* __restrict__ wg,
    const float* __restrict__ wo, unsigned short* __restrict__ dst)
{
  const int which = blockIdx.x >> 5;   // 32 blocks per 65536-elem matrix
  const float* s = (which==0)?wq:(which==1)?wk:(which==2)?wv:(which==3)?wg:wo;
  const int off = (blockIdx.x & 31) * 2048 + threadIdx.x * 8;
  f32x4 a = *(const f32x4*)(s + off);
  f32x4 b = *(const f32x4*)(s + off + 4);
  u16x8 r;
  r[0]=f2bf(a.x); r[1]=f2bf(a.y); r[2]=f2bf(a.z); r[3]=f2bf(a.w);
  r[4]=f2bf(b.x); r[5]=f2bf(b.y); r[6]=f2bf(b.z); r[7]=f2bf(b.w);
  *(u16x8*)(dst + (size_t)which*65536 + off) = r;
}

// ---------------- kernel 1: projections q,k,v(g) ---------------------------
// side 0: q_x -> q (scaled, [B,H,Q,D] bf16) and g (sigmoid, [B,Q,H,D] bf16)
// side 1: kv_x -> k ([B,H,K,D] bf16) and v^T ([B,H,D,K] bf16)
__global__ __launch_bounds__(256,2) void proj_kernel(
    const float* __restrict__ q_x, const float* __restrict__ kv_x,
    const unsigned short* __restrict__ wb,   // bf16 weights: wq,wk,wv,wg,wo
    const float* __restrict__ bg,
    unsigned short* __restrict__ qws, unsigned short* __restrict__ kws,
    unsigned short* __restrict__ vTws, unsigned short* __restrict__ gws)
{
  const int tid = threadIdx.x;
  const int w = tid >> 6, lane = tid & 63;
  const int c = lane & 15, qd = lane >> 4;
  const int side = blockIdx.x >> 8;          // 256 row-blocks per side
  const int rb = (blockIdx.x & 255) * 16;    // 16 rows per WG
  const float* X = side ? kv_x : q_x;
  const unsigned short* W0 = wb + (size_t)(side ? 1 : 0) * 65536; // wk : wq
  const unsigned short* W1 = wb + (size_t)(side ? 2 : 3) * 65536; // wv : wg
  const int hdw = w * 64;                    // wave owns 64 output channels

  const f32x4 fz = {0.f,0.f,0.f,0.f};
  f32x4 acc[2][4];
  #pragma unroll
  for (int o=0;o<2;o++)
    #pragma unroll
    for (int mt=0;mt<4;mt++) acc[o][mt] = fz;

  #pragma unroll
  for (int ks = 0; ks < 8; ks++){
    const int ko = ks*32 + qd*8;
    bf16x8 bfrag = cvtld8(X + (size_t)(rb + c)*256 + ko);  // activation rows
    #pragma unroll
    for (int mt = 0; mt < 4; mt++){
      const int hd = hdw + mt*16 + c;
      bf16x8 a0 = *(const bf16x8*)(W0 + (size_t)hd*256 + ko);
      bf16x8 a1 = *(const bf16x8*)(W1 + (size_t)hd*256 + ko);
      acc[0][mt] = MFMA(a0, bfrag, acc[0][mt]);
      acc[1][mt] = MFMA(a1, bfrag, acc[1][mt]);
    }
  }

  const int row = rb + c;
  const int b = row >> 10, rr = row & 1023;
  #pragma unroll
  for (int mt = 0; mt < 4; mt++){
    const int hd0 = hdw + mt*16 + qd*4;
    const int h = hd0 >> 5, d0 = hd0 & 31;
    f32x4 v0 = acc[0][mt], v1 = acc[1][mt];
    if (side == 0){
      const float qs = 0.17677669529663687f;   // 1/sqrt(32)
      u16x4 oq = { f2bf(v0.x*qs), f2bf(v0.y*qs), f2bf(v0.z*qs), f2bf(v0.w*qs) };
      *(u16x4*)(qws + ((size_t)((b*8 + h)*1024 + rr))*32 + d0) = oq;
      f32x4 bg4 = *(const f32x4*)(bg + hd0);
      float g0 = 1.f/(1.f + exp2f(-1.44269504f*(v1.x + bg4.x)));
      float g1 = 1.f/(1.f + exp2f(-1.44269504f*(v1.y + bg4.y)));
      float g2 = 1.f/(1.f + exp2f(-1.44269504f*(v1.z + bg4.z)));
      float g3 = 1.f/(1.f + exp2f(-1.44269504f*(v1.w + bg4.w)));
      u16x4 og = { f2bf(g0), f2bf(g1), f2bf(g2), f2bf(g3) };
      *(u16x4*)(gws + ((size_t)((b*1024 + rr)*8 + h))*32 + d0) = og;
    } else {
      u16x4 ok = { f2bf(v0.x), f2bf(v0.y), f2bf(v0.z), f2bf(v0.w) };
      *(u16x4*)(kws + ((size_t)((b*8 + h)*1024 + rr))*32 + d0) = ok;
      size_t vb = ((size_t)((b*8 + h)*32 + d0))*1024 + rr;   // V^T scatter
      vTws[vb         ] = f2bf(v1.x);
      vTws[vb + 1024  ] = f2bf(v1.y);
      vTws[vb + 2048  ] = f2bf(v1.z);
      vTws[vb + 3072  ] = f2bf(v1.w);
    }
  }
}

// ---------------- kernel 2: flash attention v3 ----------------------------
// 4 fully-independent waves per WG (16 q-rows each), NO __syncthreads.
// Software-pipelined: pair_bias (HBM stream) prefetched 2 chunks deep in
// registers; K fragments prefetched 1 chunk ahead (L2-hot). kc loop fully
// unrolled so ping-pong buffers stay in registers. Grid gives exactly
// 2 waves/SIMD, so VGPR budget up to ~250 is free -> launch_bounds(256,2).
__global__ __launch_bounds__(256,2) void attn_kernel(
    const float* __restrict__ pair_bias, const float* __restrict__ mask_bias,
    const unsigned short* __restrict__ qws, const unsigned short* __restrict__ kws,
    const unsigned short* __restrict__ vTws, const unsigned short* __restrict__ gws,
    unsigned short* __restrict__ ows)
{
  // 4 waves x 16 q-rows x 136 ushorts (128 keys + pad) = 17408 B
  __shared__ __align__(16) unsigned short pT[4*16*136];

  const int tid = threadIdx.x;
  const int w = tid >> 6, lane = tid & 63;
  const int c = lane & 15, qd = lane >> 4;
  const int bh = blockIdx.x >> 4, qb = blockIdx.x & 15;
  const int b  = bh >> 3, h = bh & 7;
  const int qrow = qb*64 + w*16 + c;

  const bf16x8 qf = *(const bf16x8*)(qws + ((size_t)bh*1024 + qrow)*32 + qd*8);
  const float* pbp = pair_bias + ((size_t)bh*1024 + qrow)*1024;
  const float* mbp = mask_bias + (size_t)b*1024;
  const unsigned short* kbase = kws  + (size_t)bh*1024*32;
  const unsigned short* vbase = vTws + (size_t)bh*32*1024;
  unsigned short* pTw = pT + w*(16*136);

  const f32x4 fz = {0.f,0.f,0.f,0.f};
  float m_i = -3.0e38f, l_i = 0.f;
  f32x4 accO0 = fz, accO1 = fz;

  // -------- software-pipeline prologue --------
  f32x4 pb0[8], pb1[8];     // pair_bias chunks kc, kc+1 (2-deep, HBM latency)
  bf16x8 afb[8];            // K fragments for chunk kc (1-deep, L2 latency)
  #pragma unroll
  for (int t = 0; t < 8; t++)
    pb0[t] = *(const f32x4*)(pbp + t*16 + qd*4);
  #pragma unroll
  for (int t = 0; t < 8; t++)
    pb1[t] = *(const f32x4*)(pbp + 128 + t*16 + qd*4);
  #pragma unroll
  for (int t = 0; t < 8; t++)
    afb[t] = *(const bf16x8*)(kbase + (size_t)(t*16 + c)*32 + qd*8);

  #pragma unroll
  for (int kc = 0; kc < 8; kc++){
    const int k0 = kc*128;
    // scores for this chunk from prefetched K fragments
    f32x4 sf[8];
    #pragma unroll
    for (int t = 0; t < 8; t++)
      sf[t] = MFMA(afb[t], qf, fz);
    // reissue K prefetch for next chunk (consumed above)
    if (kc < 7){
      #pragma unroll
      for (int t = 0; t < 8; t++)
        afb[t] = *(const bf16x8*)(kbase + (size_t)(k0 + 128 + t*16 + c)*32 + qd*8);
    }
    // biases (pair_bias from prefetch regs; mask_bias L1/L2-hot) + row max
    float cmax = -3.0e38f;
    #pragma unroll
    for (int t = 0; t < 8; t++){
      f32x4 mb = *(const f32x4*)(mbp + k0 + t*16 + qd*4);
      f32x4 pb = (kc & 1) ? pb1[t] : pb0[t];
      f32x4 s = (sf[t] + pb + mb) * 1.44269504f;
      sf[t] = s;
      cmax = fmaxf(cmax, fmaxf(fmaxf(s.x, s.y), fmaxf(s.z, s.w)));
    }
    // prefetch pair_bias for chunk kc+2 into the buffer just consumed
    if (kc < 6){
      #pragma unroll
      for (int t = 0; t < 8; t++){
        f32x4 v = *(const f32x4*)(pbp + k0 + 256 + t*16 + qd*4);
        if (kc & 1) pb1[t] = v; else pb0[t] = v;
      }
    }
    cmax = fmaxf(cmax, __shfl_xor(cmax, 16));
    cmax = fmaxf(cmax, __shfl_xor(cmax, 32));
    const float m_new = fmaxf(m_i, cmax);
    const float alpha = exp2f(m_i - m_new);
    accO0 *= alpha; accO1 *= alpha;

    // exponentiate, pack P (row=q, col=key) into per-wave LDS
    float rsum = 0.f;
    #pragma unroll
    for (int t = 0; t < 8; t++){
      f32x4 p;
      p.x = exp2f(sf[t].x - m_new);
      p.y = exp2f(sf[t].y - m_new);
      p.z = exp2f(sf[t].z - m_new);
      p.w = exp2f(sf[t].w - m_new);
      rsum += (p.x + p.y) + (p.z + p.w);
      u16x4 pk = { f2bf(p.x), f2bf(p.y), f2bf(p.z), f2bf(p.w) };
      *(u16x4*)(pTw + c*136 + t*16 + qd*4) = pk;
    }
    rsum += __shfl_xor(rsum, 16);
    rsum += __shfl_xor(rsum, 32);
    l_i = l_i*alpha + rsum;
    m_i = m_new;

    // PV: O^T(32x16) += V^T(32 x 128) * P^T(128 x 16), V from global (L2)
    #pragma unroll
    for (int ks = 0; ks < 4; ks++){
      bf16x8 pf = *(const bf16x8*)(pTw + c*136 + ks*32 + qd*8);
      bf16x8 v0 = *(const bf16x8*)(vbase + (size_t)c*1024      + k0 + ks*32 + qd*8);
      bf16x8 v1 = *(const bf16x8*)(vbase + (size_t)(16+c)*1024 + k0 + ks*32 + qd*8);
      accO0 = MFMA(v0, pf, accO0);
      accO1 = MFMA(v1, pf, accO1);
    }
  }

  // epilogue: normalize, gate, store o' bf16 [B,Q,H,D]
  const float inv_l = 1.0f / l_i;
  const size_t obase = (((size_t)b*1024 + qrow)*8 + h)*32;
  {
    u16x4 g4 = *(const u16x4*)(gws + obase + qd*4);
    u16x4 o4 = { f2bf(accO0.x*inv_l*bf2f(g4[0])),
                 f2bf(accO0.y*inv_l*bf2f(g4[1])),
                 f2bf(accO0.z*inv_l*bf2f(g4[2])),
                 f2bf(accO0.w*inv_l*bf2f(g4[3])) };
    *(u16x4*)(ows + obase + qd*4) = o4;
  }
  {
    u16x4 g4 = *(const u16x4*)(gws + obase + 16 + qd*4);
    u16x4 o4 = { f2bf(accO1.x*inv_l*bf2f(g4[0])),
                 f2bf(accO1.y*inv_l*bf2f(g4[1])),
                 f2bf(accO1.z*inv_l*bf2f(g4[2])),
                 f2bf(accO1.w*inv_l*bf2f(g4[3])) };
    *(u16x4*)(ows + obase + 16 + qd*4) = o4;
  }
}

// ---------------- kernel 3: output projection -----------------------------
__global__ __launch_bounds__(256,2) void oproj_kernel(
    const unsigned short* __restrict__ ows, const unsigned short* __restrict__ wob,
    const float* __restrict__ bo, float* __restrict__ out)
{
  const int tid = threadIdx.x;
  const int w = tid >> 6, lane = tid & 63;
  const int c = lane & 15, qd = lane >> 4;
  const int row0 = blockIdx.x * 16;
  const int i0 = w * 64;

  const f32x4 fz = {0.f,0.f,0.f,0.f};
  f32x4 acc[4] = {fz, fz, fz, fz};
  #pragma unroll
  for (int ks = 0; ks < 8; ks++){
    const int ko = ks*32 + qd*8;
    bf16x8 bfrag = *(const bf16x8*)(ows + (size_t)(row0 + c)*256 + ko);
    #pragma unroll
    for (int mt = 0; mt < 4; mt++){
      bf16x8 afrag = *(const bf16x8*)(wob + (size_t)(i0 + mt*16 + c)*256 + ko);
      acc[mt] = MFMA(afrag, bfrag, acc[mt]);
    }
  }
  #pragma unroll
  for (int mt = 0; mt < 4; mt++){
    const int i = i0 + mt*16 + qd*4;
    f32x4 bo4 = *(const f32x4*)(bo + i);
    f32x4 r = acc[mt] + bo4;
    *(f32x4*)(out + (size_t)(row0 + c)*256 + i) = r;
  }
}

extern "C" void kernel_launch(void* const* d_in, const int* in_sizes, int n_in,
                              void* d_out, int out_size, void* d_ws, size_t ws_size,
                              hipStream_t stream) {
  const float* q_x       = (const float*)d_in[0];
  const float* kv_x      = (const float*)d_in[1];
  const float* mask_bias = (const float*)d_in[2];
  const float* pair_bias = (const float*)d_in[3];
  const float* wq        = (const float*)d_in[4];
  const float* wk        = (const float*)d_in[5];
  const float* wv        = (const float*)d_in[6];
  const float* wg        = (const float*)d_in[7];
  const float* bg        = (const float*)d_in[8];
  const float* wo        = (const float*)d_in[9];
  const float* bo        = (const float*)d_in[10];

  unsigned short* ws  = (unsigned short*)d_ws;
  unsigned short* qws  = ws;                       // [B,H,Q,D]  1M
  unsigned short* kws  = ws + (1u<<20);            // [B,H,K,D]  1M
  unsigned short* vTws = ws + 2*(1u<<20);          // [B,H,D,K]  1M
  unsigned short* gws  = ws + 3*(1u<<20);          // [B,Q,H,D]  1M
  unsigned short* ows  = ws + 4*(1u<<20);          // [B,Q,H*D]  1M
  unsigned short* wb   = ws + 5*(1u<<20);          // 5 x 65536 bf16 weights

  wcvt_kernel<<<160, 256, 0, stream>>>(wq, wk, wv, wg, wo, wb);
  proj_kernel<<<512, 256, 0, stream>>>(q_x, kv_x, wb, bg, qws, kws, vTws, gws);
  attn_kernel<<<512, 256, 0, stream>>>(pair_bias, mask_bias, qws, kws, vTws, gws, ows);
  oproj_kernel<<<256, 256, 0, stream>>>(ows, wb + 4*65536, bo, (float*)d_out);
}

// Round 4
// 278.332 us; speedup vs baseline: 1.0257x; 1.0257x over previous
//
#include <hip/hip_runtime.h>
#include <cstdint>
#include <cstddef>

typedef short bf16x8 __attribute__((ext_vector_type(8)));
typedef float f32x4 __attribute__((ext_vector_type(4)));
typedef unsigned short u16x4 __attribute__((ext_vector_type(4)));
typedef unsigned short u16x8 __attribute__((ext_vector_type(8)));

#define MFMA(a,b,c) __builtin_amdgcn_mfma_f32_16x16x32_bf16((a),(b),(c),0,0,0)

__device__ __forceinline__ unsigned short f2bf(float x){
  union { float f; unsigned u; } v; v.f = x;
  unsigned r = v.u + 0x7FFFu + ((v.u >> 16) & 1u);  // RNE
  return (unsigned short)(r >> 16);
}
__device__ __forceinline__ float bf2f(unsigned short b){
  union { unsigned u; float f; } v; v.u = ((unsigned)b) << 16;
  return v.f;
}
__device__ __forceinline__ bf16x8 cvtld8(const float* p){
  f32x4 a = *(const f32x4*)p;
  f32x4 b = *(const f32x4*)(p + 4);
  bf16x8 r;
  r[0]=(short)f2bf(a.x); r[1]=(short)f2bf(a.y);
  r[2]=(short)f2bf(a.z); r[3]=(short)f2bf(a.w);
  r[4]=(short)f2bf(b.x); r[5]=(short)f2bf(b.y);
  r[6]=(short)f2bf(b.z); r[7]=(short)f2bf(b.w);
  return r;
}

// ---------------- kernel 0: fp32 weights -> bf16 (wq,wk,wv,wg,wo) ----------
__global__ __launch_bounds__(256) void wcvt_kernel(
    const float* __restrict__ wq, const float* __restrict__ wk,
    const float* __restrict__ wv, const float* __restrict__ wg,
    const float* __restrict__ wo, unsigned short* __restrict__ dst)
{
  const int which = blockIdx.x >> 5;   // 32 blocks per 65536-elem matrix
  const float* s = (which==0)?wq:(which==1)?wk:(which==2)?wv:(which==3)?wg:wo;
  const int off = (blockIdx.x & 31) * 2048 + threadIdx.x * 8;
  f32x4 a = *(const f32x4*)(s + off);
  f32x4 b = *(const f32x4*)(s + off + 4);
  u16x8 r;
  r[0]=f2bf(a.x); r[1]=f2bf(a.y); r[2]=f2bf(a.z); r[3]=f2bf(a.w);
  r[4]=f2bf(b.x); r[5]=f2bf(b.y); r[6]=f2bf(b.z); r[7]=f2bf(b.w);
  *(u16x8*)(dst + (size_t)which*65536 + off) = r;
}

// ---------------- kernel 1: projections q,k,v(g) ---------------------------
__global__ __launch_bounds__(256,2) void proj_kernel(
    const float* __restrict__ q_x, const float* __restrict__ kv_x,
    const unsigned short* __restrict__ wb,   // bf16 weights: wq,wk,wv,wg,wo
    const float* __restrict__ bg,
    unsigned short* __restrict__ qws, unsigned short* __restrict__ kws,
    unsigned short* __restrict__ vTws, unsigned short* __restrict__ gws)
{
  const int tid = threadIdx.x;
  const int w = tid >> 6, lane = tid & 63;
  const int c = lane & 15, qd = lane >> 4;
  const int side = blockIdx.x >> 8;          // 256 row-blocks per side
  const int rb = (blockIdx.x & 255) * 16;    // 16 rows per WG
  const float* X = side ? kv_x : q_x;
  const unsigned short* W0 = wb + (size_t)(side ? 1 : 0) * 65536; // wk : wq
  const unsigned short* W1 = wb + (size_t)(side ? 2 : 3) * 65536; // wv : wg
  const int hdw = w * 64;                    // wave owns 64 output channels

  const f32x4 fz = {0.f,0.f,0.f,0.f};
  f32x4 acc[2][4];
  #pragma unroll
  for (int o=0;o<2;o++)
    #pragma unroll
    for (int mt=0;mt<4;mt++) acc[o][mt] = fz;

  #pragma unroll
  for (int ks = 0; ks < 8; ks++){
    const int ko = ks*32 + qd*8;
    bf16x8 bfrag = cvtld8(X + (size_t)(rb + c)*256 + ko);  // activation rows
    #pragma unroll
    for (int mt = 0; mt < 4; mt++){
      const int hd = hdw + mt*16 + c;
      bf16x8 a0 = *(const bf16x8*)(W0 + (size_t)hd*256 + ko);
      bf16x8 a1 = *(const bf16x8*)(W1 + (size_t)hd*256 + ko);
      acc[0][mt] = MFMA(a0, bfrag, acc[0][mt]);
      acc[1][mt] = MFMA(a1, bfrag, acc[1][mt]);
    }
  }

  const int row = rb + c;
  const int b = row >> 10, rr = row & 1023;
  #pragma unroll
  for (int mt = 0; mt < 4; mt++){
    const int hd0 = hdw + mt*16 + qd*4;
    const int h = hd0 >> 5, d0 = hd0 & 31;
    f32x4 v0 = acc[0][mt], v1 = acc[1][mt];
    if (side == 0){
      const float qs = 0.17677669529663687f;   // 1/sqrt(32)
      u16x4 oq = { f2bf(v0.x*qs), f2bf(v0.y*qs), f2bf(v0.z*qs), f2bf(v0.w*qs) };
      *(u16x4*)(qws + ((size_t)((b*8 + h)*1024 + rr))*32 + d0) = oq;
      f32x4 bg4 = *(const f32x4*)(bg + hd0);
      float g0 = 1.f/(1.f + exp2f(-1.44269504f*(v1.x + bg4.x)));
      float g1 = 1.f/(1.f + exp2f(-1.44269504f*(v1.y + bg4.y)));
      float g2 = 1.f/(1.f + exp2f(-1.44269504f*(v1.z + bg4.z)));
      float g3 = 1.f/(1.f + exp2f(-1.44269504f*(v1.w + bg4.w)));
      u16x4 og = { f2bf(g0), f2bf(g1), f2bf(g2), f2bf(g3) };
      *(u16x4*)(gws + ((size_t)((b*1024 + rr)*8 + h))*32 + d0) = og;
    } else {
      u16x4 ok = { f2bf(v0.x), f2bf(v0.y), f2bf(v0.z), f2bf(v0.w) };
      *(u16x4*)(kws + ((size_t)((b*8 + h)*1024 + rr))*32 + d0) = ok;
      size_t vb = ((size_t)((b*8 + h)*32 + d0))*1024 + rr;   // V^T scatter
      vTws[vb         ] = f2bf(v1.x);
      vTws[vb + 1024  ] = f2bf(v1.y);
      vTws[vb + 2048  ] = f2bf(v1.z);
      vTws[vb + 3072  ] = f2bf(v1.w);
    }
  }
}

// ---------------- kernel 2: flash attention, split-K x2 --------------------
// grid 1024: split = bid>>9 handles keys [split*512, split*512+512).
// 4 waves/WG x 16 q-rows, barrier-free; 4096 waves -> 4 waves/SIMD.
// Partial (unnormalized O^T, m, l) written fp32 to workspace; combine_kernel
// merges. Modest 1-chunk-ahead prefetch of K-frags + pair_bias (64 VGPRs).
__global__ __launch_bounds__(256,4) void attn_kernel(
    const float* __restrict__ pair_bias, const float* __restrict__ mask_bias,
    const unsigned short* __restrict__ qws, const unsigned short* __restrict__ kws,
    const unsigned short* __restrict__ vTws,
    float* __restrict__ pO, float* __restrict__ pML)
{
  // 4 waves x 16 q-rows x 136 ushorts (128 keys + pad) = 17408 B
  __shared__ __align__(16) unsigned short pT[4*16*136];

  const int tid = threadIdx.x;
  const int w = tid >> 6, lane = tid & 63;
  const int c = lane & 15, qd = lane >> 4;
  const int split = blockIdx.x >> 9;
  const int rblk  = blockIdx.x & 511;
  const int bh = rblk >> 4, qb = rblk & 15;
  const int b  = bh >> 3;
  const int qrow = qb*64 + w*16 + c;
  const int kbeg = split*512;

  const bf16x8 qf = *(const bf16x8*)(qws + ((size_t)bh*1024 + qrow)*32 + qd*8);
  const float* pbp = pair_bias + ((size_t)bh*1024 + qrow)*1024 + kbeg;
  const float* mbp = mask_bias + (size_t)b*1024 + kbeg;
  const unsigned short* kbase = kws  + ((size_t)bh*1024 + kbeg)*32;
  const unsigned short* vbase = vTws + (size_t)bh*32*1024 + kbeg;
  unsigned short* pTw = pT + w*(16*136);

  const f32x4 fz = {0.f,0.f,0.f,0.f};
  float m_i = -3.0e38f, l_i = 0.f;
  f32x4 accO0 = fz, accO1 = fz;

  // 1-chunk-ahead prefetch buffers
  bf16x8 afb[8];
  f32x4  pbb[8];
  #pragma unroll
  for (int t = 0; t < 8; t++){
    afb[t] = *(const bf16x8*)(kbase + (size_t)(t*16 + c)*32 + qd*8);
    pbb[t] = *(const f32x4*)(pbp + t*16 + qd*4);
  }

  #pragma unroll
  for (int kc = 0; kc < 4; kc++){
    const int k0 = kc*128;
    // scores from prefetched K; bias-add consumes prefetched pb immediately
    f32x4 sf[8];
    float cmax = -3.0e38f;
    #pragma unroll
    for (int t = 0; t < 8; t++){
      f32x4 s = MFMA(afb[t], qf, fz);
      f32x4 mb = *(const f32x4*)(mbp + k0 + t*16 + qd*4);
      s = (s + pbb[t] + mb) * 1.44269504f;
      sf[t] = s;
      cmax = fmaxf(cmax, fmaxf(fmaxf(s.x, s.y), fmaxf(s.z, s.w)));
    }
    // reissue prefetch for next chunk (buffers just consumed)
    if (kc < 3){
      #pragma unroll
      for (int t = 0; t < 8; t++){
        afb[t] = *(const bf16x8*)(kbase + (size_t)(k0 + 128 + t*16 + c)*32 + qd*8);
        pbb[t] = *(const f32x4*)(pbp + k0 + 128 + t*16 + qd*4);
      }
    }
    cmax = fmaxf(cmax, __shfl_xor(cmax, 16));
    cmax = fmaxf(cmax, __shfl_xor(cmax, 32));
    const float m_new = fmaxf(m_i, cmax);
    const float alpha = exp2f(m_i - m_new);
    accO0 *= alpha; accO1 *= alpha;

    // exponentiate, pack P into per-wave LDS
    float rsum = 0.f;
    #pragma unroll
    for (int t = 0; t < 8; t++){
      f32x4 p;
      p.x = exp2f(sf[t].x - m_new);
      p.y = exp2f(sf[t].y - m_new);
      p.z = exp2f(sf[t].z - m_new);
      p.w = exp2f(sf[t].w - m_new);
      rsum += (p.x + p.y) + (p.z + p.w);
      u16x4 pk = { f2bf(p.x), f2bf(p.y), f2bf(p.z), f2bf(p.w) };
      *(u16x4*)(pTw + c*136 + t*16 + qd*4) = pk;
    }
    rsum += __shfl_xor(rsum, 16);
    rsum += __shfl_xor(rsum, 32);
    l_i = l_i*alpha + rsum;
    m_i = m_new;

    // PV: O^T(32x16) += V^T(32 x 128) * P^T(128 x 16), V from global (L2)
    #pragma unroll
    for (int ks = 0; ks < 4; ks++){
      bf16x8 pf = *(const bf16x8*)(pTw + c*136 + ks*32 + qd*8);
      bf16x8 v0 = *(const bf16x8*)(vbase + (size_t)c*1024      + k0 + ks*32 + qd*8);
      bf16x8 v1 = *(const bf16x8*)(vbase + (size_t)(16+c)*1024 + k0 + ks*32 + qd*8);
      accO0 = MFMA(v0, pf, accO0);
      accO1 = MFMA(v1, pf, accO1);
    }
  }

  // epilogue: store fp32 partials (unnormalized O, plus m,l)
  const size_t prow = (size_t)split*32768 + (size_t)bh*1024 + qrow;
  *(f32x4*)(pO + prow*32 + qd*4)      = accO0;
  *(f32x4*)(pO + prow*32 + 16 + qd*4) = accO1;
  if (qd == 0){
    pML[prow*2]     = m_i;
    pML[prow*2 + 1] = l_i;
  }
}

// ---------------- kernel 2b: merge the two splits, gate, emit bf16 --------
__global__ __launch_bounds__(256) void combine_kernel(
    const float* __restrict__ pO, const float* __restrict__ pML,
    const unsigned short* __restrict__ gws, unsigned short* __restrict__ ows)
{
  const int gtid = blockIdx.x*256 + threadIdx.x;
  const int row = gtid >> 2, part = gtid & 3;   // row in [0,32768)
  const int d0 = part*8;
  const float m0 = pML[(size_t)row*2],           l0 = pML[(size_t)row*2 + 1];
  const float m1 = pML[(size_t)(32768 + row)*2], l1 = pML[(size_t)(32768 + row)*2 + 1];
  const float m  = fmaxf(m0, m1);
  const float a0 = exp2f(m0 - m), a1 = exp2f(m1 - m);
  const float inv = 1.0f / (l0*a0 + l1*a1);
  f32x4 x0 = *(const f32x4*)(pO + (size_t)row*32 + d0);
  f32x4 x1 = *(const f32x4*)(pO + (size_t)row*32 + d0 + 4);
  f32x4 y0 = *(const f32x4*)(pO + 32768ull*32 + (size_t)row*32 + d0);
  f32x4 y1 = *(const f32x4*)(pO + 32768ull*32 + (size_t)row*32 + d0 + 4);
  const int bh = row >> 10, qrow = row & 1023, b = bh >> 3, h = bh & 7;
  const size_t obase = (((size_t)b*1024 + qrow)*8 + h)*32 + d0;
  u16x8 g8 = *(const u16x8*)(gws + obase);
  const float s0 = a0*inv, s1 = a1*inv;
  f32x4 o0 = x0*s0 + y0*s1;
  f32x4 o1 = x1*s0 + y1*s1;
  u16x8 r8;
  r8[0] = f2bf(o0.x*bf2f(g8[0]));
  r8[1] = f2bf(o0.y*bf2f(g8[1]));
  r8[2] = f2bf(o0.z*bf2f(g8[2]));
  r8[3] = f2bf(o0.w*bf2f(g8[3]));
  r8[4] = f2bf(o1.x*bf2f(g8[4]));
  r8[5] = f2bf(o1.y*bf2f(g8[5]));
  r8[6] = f2bf(o1.z*bf2f(g8[6]));
  r8[7] = f2bf(o1.w*bf2f(g8[7]));
  *(u16x8*)(ows + obase) = r8;
}

// ---------------- kernel 3: output projection -----------------------------
__global__ __launch_bounds__(256,2) void oproj_kernel(
    const unsigned short* __restrict__ ows, const unsigned short* __restrict__ wob,
    const float* __restrict__ bo, float* __restrict__ out)
{
  const int tid = threadIdx.x;
  const int w = tid >> 6, lane = tid & 63;
  const int c = lane & 15, qd = lane >> 4;
  const int row0 = blockIdx.x * 16;
  const int i0 = w * 64;

  const f32x4 fz = {0.f,0.f,0.f,0.f};
  f32x4 acc[4] = {fz, fz, fz, fz};
  #pragma unroll
  for (int ks = 0; ks < 8; ks++){
    const int ko = ks*32 + qd*8;
    bf16x8 bfrag = *(const bf16x8*)(ows + (size_t)(row0 + c)*256 + ko);
    #pragma unroll
    for (int mt = 0; mt < 4; mt++){
      bf16x8 afrag = *(const bf16x8*)(wob + (size_t)(i0 + mt*16 + c)*256 + ko);
      acc[mt] = MFMA(afrag, bfrag, acc[mt]);
    }
  }
  #pragma unroll
  for (int mt = 0; mt < 4; mt++){
    const int i = i0 + mt*16 + qd*4;
    f32x4 bo4 = *(const f32x4*)(bo + i);
    f32x4 r = acc[mt] + bo4;
    *(f32x4*)(out + (size_t)(row0 + c)*256 + i) = r;
  }
}

extern "C" void kernel_launch(void* const* d_in, const int* in_sizes, int n_in,
                              void* d_out, int out_size, void* d_ws, size_t ws_size,
                              hipStream_t stream) {
  const float* q_x       = (const float*)d_in[0];
  const float* kv_x      = (const float*)d_in[1];
  const float* mask_bias = (const float*)d_in[2];
  const float* pair_bias = (const float*)d_in[3];
  const float* wq        = (const float*)d_in[4];
  const float* wk        = (const float*)d_in[5];
  const float* wv        = (const float*)d_in[6];
  const float* wg        = (const float*)d_in[7];
  const float* bg        = (const float*)d_in[8];
  const float* wo        = (const float*)d_in[9];
  const float* bo        = (const float*)d_in[10];

  char* base = (char*)d_ws;
  unsigned short* qws  = (unsigned short*)(base);                 // 2 MB
  unsigned short* kws  = (unsigned short*)(base + (2u<<20));      // 2 MB
  unsigned short* vTws = (unsigned short*)(base + (4u<<20));      // 2 MB
  unsigned short* gws  = (unsigned short*)(base + (6u<<20));      // 2 MB
  unsigned short* ows  = (unsigned short*)(base + (8u<<20));      // 2 MB
  unsigned short* wb   = (unsigned short*)(base + (10u<<20));     // 0.625 MB
  float*          pO   = (float*)(base + (12u<<20));              // 8 MB
  float*          pML  = (float*)(base + (20u<<20));              // 0.5 MB

  wcvt_kernel<<<160, 256, 0, stream>>>(wq, wk, wv, wg, wo, wb);
  proj_kernel<<<512, 256, 0, stream>>>(q_x, kv_x, wb, bg, qws, kws, vTws, gws);
  attn_kernel<<<1024, 256, 0, stream>>>(pair_bias, mask_bias, qws, kws, vTws, pO, pML);
  combine_kernel<<<512, 256, 0, stream>>>(pO, pML, gws, ows);
  oproj_kernel<<<256, 256, 0, stream>>>(ows, wb + 4*65536, bo, (float*)d_out);
}

// Round 5
// 258.498 us; speedup vs baseline: 1.1044x; 1.0767x over previous
//
#include <hip/hip_runtime.h>
#include <cstdint>
#include <cstddef>

typedef short bf16x8 __attribute__((ext_vector_type(8)));
typedef float f32x4 __attribute__((ext_vector_type(4)));
typedef unsigned short u16x4 __attribute__((ext_vector_type(4)));
typedef unsigned short u16x8 __attribute__((ext_vector_type(8)));

#define MFMA(a,b,c) __builtin_amdgcn_mfma_f32_16x16x32_bf16((a),(b),(c),0,0,0)

__device__ __forceinline__ unsigned short f2bf(float x){
  union { float f; unsigned u; } v; v.f = x;
  unsigned r = v.u + 0x7FFFu + ((v.u >> 16) & 1u);  // RNE
  return (unsigned short)(r >> 16);
}
__device__ __forceinline__ float bf2f(unsigned short b){
  union { unsigned u; float f; } v; v.u = ((unsigned)b) << 16;
  return v.f;
}
__device__ __forceinline__ bf16x8 cvtld8(const float* p){
  f32x4 a = *(const f32x4*)p;
  f32x4 b = *(const f32x4*)(p + 4);
  bf16x8 r;
  r[0]=(short)f2bf(a.x); r[1]=(short)f2bf(a.y);
  r[2]=(short)f2bf(a.z); r[3]=(short)f2bf(a.w);
  r[4]=(short)f2bf(b.x); r[5]=(short)f2bf(b.y);
  r[6]=(short)f2bf(b.z); r[7]=(short)f2bf(b.w);
  return r;
}

// async global->LDS DMA, 16B per lane; lds base must be wave-uniform.
__device__ __forceinline__ void dma16(const void* g, void* l){
  __builtin_amdgcn_global_load_lds(
      (const __attribute__((address_space(1))) unsigned int*)g,
      (__attribute__((address_space(3))) unsigned int*)l, 16, 0, 0);
}

// ---------------- kernel 0: fp32 weights -> bf16 (wq,wk,wv,wg,wo) ----------
__global__ __launch_bounds__(256) void wcvt_kernel(
    const float* __restrict__ wq, const float* __restrict__ wk,
    const float* __restrict__ wv, const float* __restrict__ wg,
    const float* __restrict__ wo, unsigned short* __restrict__ dst)
{
  const int which = blockIdx.x >> 5;   // 32 blocks per 65536-elem matrix
  const float* s = (which==0)?wq:(which==1)?wk:(which==2)?wv:(which==3)?wg:wo;
  const int off = (blockIdx.x & 31) * 2048 + threadIdx.x * 8;
  f32x4 a = *(const f32x4*)(s + off);
  f32x4 b = *(const f32x4*)(s + off + 4);
  u16x8 r;
  r[0]=f2bf(a.x); r[1]=f2bf(a.y); r[2]=f2bf(a.z); r[3]=f2bf(a.w);
  r[4]=f2bf(b.x); r[5]=f2bf(b.y); r[6]=f2bf(b.z); r[7]=f2bf(b.w);
  *(u16x8*)(dst + (size_t)which*65536 + off) = r;
}

// ---------------- kernel 1: projections q,k,v(g) ---------------------------
// q is pre-scaled by log2(e)/sqrt(D) so attention scores come out in the
// log2 domain straight from the MFMA.
__global__ __launch_bounds__(256,2) void proj_kernel(
    const float* __restrict__ q_x, const float* __restrict__ kv_x,
    const unsigned short* __restrict__ wb,   // bf16 weights: wq,wk,wv,wg,wo
    const float* __restrict__ bg,
    unsigned short* __restrict__ qws, unsigned short* __restrict__ kws,
    unsigned short* __restrict__ vTws, unsigned short* __restrict__ gws)
{
  const int tid = threadIdx.x;
  const int w = tid >> 6, lane = tid & 63;
  const int c = lane & 15, qd = lane >> 4;
  const int side = blockIdx.x >> 8;          // 256 row-blocks per side
  const int rb = (blockIdx.x & 255) * 16;    // 16 rows per WG
  const float* X = side ? kv_x : q_x;
  const unsigned short* W0 = wb + (size_t)(side ? 1 : 0) * 65536; // wk : wq
  const unsigned short* W1 = wb + (size_t)(side ? 2 : 3) * 65536; // wv : wg
  const int hdw = w * 64;                    // wave owns 64 output channels

  const f32x4 fz = {0.f,0.f,0.f,0.f};
  f32x4 acc[2][4];
  #pragma unroll
  for (int o=0;o<2;o++)
    #pragma unroll
    for (int mt=0;mt<4;mt++) acc[o][mt] = fz;

  #pragma unroll
  for (int ks = 0; ks < 8; ks++){
    const int ko = ks*32 + qd*8;
    bf16x8 bfrag = cvtld8(X + (size_t)(rb + c)*256 + ko);  // activation rows
    #pragma unroll
    for (int mt = 0; mt < 4; mt++){
      const int hd = hdw + mt*16 + c;
      bf16x8 a0 = *(const bf16x8*)(W0 + (size_t)hd*256 + ko);
      bf16x8 a1 = *(const bf16x8*)(W1 + (size_t)hd*256 + ko);
      acc[0][mt] = MFMA(a0, bfrag, acc[0][mt]);
      acc[1][mt] = MFMA(a1, bfrag, acc[1][mt]);
    }
  }

  const int row = rb + c;
  const int b = row >> 10, rr = row & 1023;
  #pragma unroll
  for (int mt = 0; mt < 4; mt++){
    const int hd0 = hdw + mt*16 + qd*4;
    const int h = hd0 >> 5, d0 = hd0 & 31;
    f32x4 v0 = acc[0][mt], v1 = acc[1][mt];
    if (side == 0){
      const float qs = 0.2550348612f;   // log2(e)/sqrt(32)
      u16x4 oq = { f2bf(v0.x*qs), f2bf(v0.y*qs), f2bf(v0.z*qs), f2bf(v0.w*qs) };
      *(u16x4*)(qws + ((size_t)((b*8 + h)*1024 + rr))*32 + d0) = oq;
      f32x4 bg4 = *(const f32x4*)(bg + hd0);
      float g0 = 1.f/(1.f + exp2f(-1.44269504f*(v1.x + bg4.x)));
      float g1 = 1.f/(1.f + exp2f(-1.44269504f*(v1.y + bg4.y)));
      float g2 = 1.f/(1.f + exp2f(-1.44269504f*(v1.z + bg4.z)));
      float g3 = 1.f/(1.f + exp2f(-1.44269504f*(v1.w + bg4.w)));
      u16x4 og = { f2bf(g0), f2bf(g1), f2bf(g2), f2bf(g3) };
      *(u16x4*)(gws + ((size_t)((b*1024 + rr)*8 + h))*32 + d0) = og;
    } else {
      u16x4 ok = { f2bf(v0.x), f2bf(v0.y), f2bf(v0.z), f2bf(v0.w) };
      *(u16x4*)(kws + ((size_t)((b*8 + h)*1024 + rr))*32 + d0) = ok;
      size_t vb = ((size_t)((b*8 + h)*32 + d0))*1024 + rr;   // V^T scatter
      vTws[vb         ] = f2bf(v1.x);
      vTws[vb + 1024  ] = f2bf(v1.y);
      vTws[vb + 2048  ] = f2bf(v1.z);
      vTws[vb + 3072  ] = f2bf(v1.w);
    }
  }
}

// ---------------- kernel 2: flash attention v5 (LDS-DMA streaming) --------
// 4 independent waves/WG (16 q-rows each), NO __syncthreads.
// pair_bias streamed via global_load_lds into a per-wave double-buffered
// LDS region (zero VGPR cost -> deep MLP); chunk = 64 keys, 16 chunks.
// Manual s_waitcnt vmcnt(8) orders DMA vs ds_read; V loads issue BEFORE the
// next-chunk DMA so the compiler's exact waitcnt keeps prefetch in flight.
// Bias enters via the MFMA C operand: C = (pb+mb)*log2e, q pre-scaled.
__global__ __launch_bounds__(256,2) void attn_kernel(
    const float* __restrict__ pair_bias, const float* __restrict__ mask_bias,
    const unsigned short* __restrict__ qws, const unsigned short* __restrict__ kws,
    const unsigned short* __restrict__ vTws, const unsigned short* __restrict__ gws,
    unsigned short* __restrict__ ows)
{
  // LDS: pb dbuf 4 waves x 2 x 4096 B = 32768; P 4 waves x 16 x 80 us = 10240
  __shared__ __align__(16) unsigned char smem[43008];

  const int tid = threadIdx.x;
  const int w = tid >> 6, lane = tid & 63;
  const int c = lane & 15, qd = lane >> 4;
  const int rl = lane >> 4, p16 = lane & 15;      // DMA lane decomposition
  const int bh = blockIdx.x >> 4, qb = blockIdx.x & 15;
  const int b  = bh >> 3, h = bh & 7;
  const int qrow = qb*64 + w*16 + c;

  float* mybuf = (float*)(smem + w*8192);                     // 2 x 1024 floats
  unsigned short* pTw = (unsigned short*)(smem + 32768) + w*(16*80);

  const bf16x8 qf = *(const bf16x8*)(qws + ((size_t)bh*1024 + qrow)*32 + qd*8);
  const float* pbw = pair_bias + ((size_t)bh*1024 + qb*64 + w*16)*1024; // wave row base
  const float* mbp = mask_bias + (size_t)b*1024;
  const unsigned short* kbase = kws  + (size_t)bh*1024*32;
  const unsigned short* vbase = vTws + (size_t)bh*32*1024;

  const f32x4 fz = {0.f,0.f,0.f,0.f};
  float m_i = -3.0e38f, l_i = 0.f;
  f32x4 accO0 = fz, accO1 = fz;

  // DMA prologue: chunk 0 into buffer 0.  Swizzle: row r=4j+rl holds
  // key-group (p16^r) at LDS pos p16 (breaks the 16-way read conflict).
  #pragma unroll
  for (int j = 0; j < 4; j++){
    const int r = 4*j + rl;
    dma16(pbw + (size_t)r*1024 + ((p16 ^ r) << 2), mybuf + j*256);
  }

  for (int kc = 0; kc < 16; kc++){
    const int k0 = kc*64;
    float* cur = mybuf + (kc & 1)*1024;
    float* nxt = mybuf + ((kc + 1) & 1)*1024;

    // K fragments + mask_bias for this chunk (L2/L1-hot vector loads)
    bf16x8 af[4];
    f32x4  mb[4];
    #pragma unroll
    for (int t = 0; t < 4; t++){
      af[t] = *(const bf16x8*)(kbase + (size_t)(k0 + t*16 + c)*32 + qd*8);
      mb[t] = *(const f32x4*)(mbp + k0 + t*16 + qd*4);
    }

    // wait for this chunk's pb DMA (queue: DMA_kc(4), K(4), mb(4) = 12)
    asm volatile("s_waitcnt vmcnt(8)" ::: "memory");

    // scores: S^T tile t, C-operand carries (pb+mb)*log2e
    f32x4 sf[4];
    float cmax = -3.0e38f;
    #pragma unroll
    for (int t = 0; t < 4; t++){
      f32x4 pb4 = *(const f32x4*)(cur + c*64 + (((t*4 + qd) ^ c) << 2));
      f32x4 C = (pb4 + mb[t]) * 1.44269504f;
      f32x4 s = MFMA(af[t], qf, C);
      sf[t] = s;
      cmax = fmaxf(cmax, fmaxf(fmaxf(s.x, s.y), fmaxf(s.z, s.w)));
    }
    cmax = fmaxf(cmax, __shfl_xor(cmax, 16));
    cmax = fmaxf(cmax, __shfl_xor(cmax, 32));
    const float m_new = fmaxf(m_i, cmax);
    const float alpha = exp2f(m_i - m_new);
    accO0 *= alpha; accO1 *= alpha;

    // exponentiate + pack P (row=q, col=key) into per-wave LDS
    float rsum = 0.f;
    #pragma unroll
    for (int t = 0; t < 4; t++){
      f32x4 p;
      p.x = exp2f(sf[t].x - m_new);
      p.y = exp2f(sf[t].y - m_new);
      p.z = exp2f(sf[t].z - m_new);
      p.w = exp2f(sf[t].w - m_new);
      rsum += (p.x + p.y) + (p.z + p.w);
      u16x4 pk = { f2bf(p.x), f2bf(p.y), f2bf(p.z), f2bf(p.w) };
      *(u16x4*)(pTw + c*80 + t*16 + qd*4) = pk;
    }
    rsum += __shfl_xor(rsum, 16);
    rsum += __shfl_xor(rsum, 32);
    l_i = l_i*alpha + rsum;
    m_i = m_new;

    // V fragments FIRST (so their waitcnt leaves the next DMA in flight)
    bf16x8 v00 = *(const bf16x8*)(vbase + (size_t)c*1024      + k0 + qd*8);
    bf16x8 v10 = *(const bf16x8*)(vbase + (size_t)(16+c)*1024 + k0 + qd*8);
    bf16x8 v01 = *(const bf16x8*)(vbase + (size_t)c*1024      + k0 + 32 + qd*8);
    bf16x8 v11 = *(const bf16x8*)(vbase + (size_t)(16+c)*1024 + k0 + 32 + qd*8);

    asm volatile("" ::: "memory");   // pin order: V loads above, DMA below

    // issue next chunk's pb DMA (stays in flight through PV + next K loads)
    if (kc < 15){
      #pragma unroll
      for (int j = 0; j < 4; j++){
        const int r = 4*j + rl;
        dma16(pbw + (size_t)r*1024 + (k0 + 64) + ((p16 ^ r) << 2), nxt + j*256);
      }
    }

    // PV: O^T(32x16) += V^T(32x64) * P^T(64x16)
    bf16x8 pf0 = *(const bf16x8*)(pTw + c*80 + qd*8);
    bf16x8 pf1 = *(const bf16x8*)(pTw + c*80 + 32 + qd*8);
    accO0 = MFMA(v00, pf0, accO0);
    accO1 = MFMA(v10, pf0, accO1);
    accO0 = MFMA(v01, pf1, accO0);
    accO1 = MFMA(v11, pf1, accO1);
  }

  // epilogue: normalize, gate, store o' bf16 [B,Q,H,D]
  const float inv_l = 1.0f / l_i;
  const size_t obase = (((size_t)b*1024 + qrow)*8 + h)*32;
  {
    u16x4 g4 = *(const u16x4*)(gws + obase + qd*4);
    u16x4 o4 = { f2bf(accO0.x*inv_l*bf2f(g4[0])),
                 f2bf(accO0.y*inv_l*bf2f(g4[1])),
                 f2bf(accO0.z*inv_l*bf2f(g4[2])),
                 f2bf(accO0.w*inv_l*bf2f(g4[3])) };
    *(u16x4*)(ows + obase + qd*4) = o4;
  }
  {
    u16x4 g4 = *(const u16x4*)(gws + obase + 16 + qd*4);
    u16x4 o4 = { f2bf(accO1.x*inv_l*bf2f(g4[0])),
                 f2bf(accO1.y*inv_l*bf2f(g4[1])),
                 f2bf(accO1.z*inv_l*bf2f(g4[2])),
                 f2bf(accO1.w*inv_l*bf2f(g4[3])) };
    *(u16x4*)(ows + obase + 16 + qd*4) = o4;
  }
}

// ---------------- kernel 3: output projection -----------------------------
__global__ __launch_bounds__(256,2) void oproj_kernel(
    const unsigned short* __restrict__ ows, const unsigned short* __restrict__ wob,
    const float* __restrict__ bo, float* __restrict__ out)
{
  const int tid = threadIdx.x;
  const int w = tid >> 6, lane = tid & 63;
  const int c = lane & 15, qd = lane >> 4;
  const int row0 = blockIdx.x * 16;
  const int i0 = w * 64;

  const f32x4 fz = {0.f,0.f,0.f,0.f};
  f32x4 acc[4] = {fz, fz, fz, fz};
  #pragma unroll
  for (int ks = 0; ks < 8; ks++){
    const int ko = ks*32 + qd*8;
    bf16x8 bfrag = *(const bf16x8*)(ows + (size_t)(row0 + c)*256 + ko);
    #pragma unroll
    for (int mt = 0; mt < 4; mt++){
      bf16x8 afrag = *(const bf16x8*)(wob + (size_t)(i0 + mt*16 + c)*256 + ko);
      acc[mt] = MFMA(afrag, bfrag, acc[mt]);
    }
  }
  #pragma unroll
  for (int mt = 0; mt < 4; mt++){
    const int i = i0 + mt*16 + qd*4;
    f32x4 bo4 = *(const f32x4*)(bo + i);
    f32x4 r = acc[mt] + bo4;
    *(f32x4*)(out + (size_t)(row0 + c)*256 + i) = r;
  }
}

extern "C" void kernel_launch(void* const* d_in, const int* in_sizes, int n_in,
                              void* d_out, int out_size, void* d_ws, size_t ws_size,
                              hipStream_t stream) {
  const float* q_x       = (const float*)d_in[0];
  const float* kv_x      = (const float*)d_in[1];
  const float* mask_bias = (const float*)d_in[2];
  const float* pair_bias = (const float*)d_in[3];
  const float* wq        = (const float*)d_in[4];
  const float* wk        = (const float*)d_in[5];
  const float* wv        = (const float*)d_in[6];
  const float* wg        = (const float*)d_in[7];
  const float* bg        = (const float*)d_in[8];
  const float* wo        = (const float*)d_in[9];
  const float* bo        = (const float*)d_in[10];

  char* base = (char*)d_ws;
  unsigned short* qws  = (unsigned short*)(base);                 // 2 MB
  unsigned short* kws  = (unsigned short*)(base + (2u<<20));      // 2 MB
  unsigned short* vTws = (unsigned short*)(base + (4u<<20));      // 2 MB
  unsigned short* gws  = (unsigned short*)(base + (6u<<20));      // 2 MB
  unsigned short* ows  = (unsigned short*)(base + (8u<<20));      // 2 MB
  unsigned short* wb   = (unsigned short*)(base + (10u<<20));     // 0.625 MB

  wcvt_kernel<<<160, 256, 0, stream>>>(wq, wk, wv, wg, wo, wb);
  proj_kernel<<<512, 256, 0, stream>>>(q_x, kv_x, wb, bg, qws, kws, vTws, gws);
  attn_kernel<<<512, 256, 0, stream>>>(pair_bias, mask_bias, qws, kws, vTws, gws, ows);
  oproj_kernel<<<256, 256, 0, stream>>>(ows, wb + 4*65536, bo, (float*)d_out);
}